// Round 2
// baseline (350.576 us; speedup 1.0000x reference)
//
#include <hip/hip_runtime.h>
#include <stdint.h>

#define K_TAGS   32
#define START_IX 30
#define END_IX   31

typedef float v2f __attribute__((ext_vector_type(2)));

// DPP row_ror:N within each 16-lane row: dst[i] = src[(i-N)&15] (data moves to higher lanes)
template<int N>
__device__ __forceinline__ float ror16(float x) {
    return __int_as_float(__builtin_amdgcn_mov_dpp(__float_as_int(x), 0x120 + N, 0xF, 0xF, false));
}

// value of x at lane l^32 (full-rate VALU permlane, gfx950)
__device__ __forceinline__ float xswap32(float x, bool hi) {
    float a = x, b = x;
    asm volatile("v_permlane32_swap_b32 %0, %1" : "+v"(a), "+v"(b));
    // new a[l>=32] = x[l-32]; new b[l<32] = x[l+32]
    return hi ? a : b;
}

// Lane map: i = l&15 (pos in row), batch-half = (l>>4)&1, tag-half = l>>5.
// tag c = i + 16*(l>>5). Rows pair under l^32 within a batch (permlane32_swap).
// State u[c] = exp(alpha[c]) * 2^-off, off tracked exactly (integer, power-of-2 renorm).
__global__ __launch_bounds__(64) void crf_fwd_kernel(
    const float* __restrict__ frames,   // [B][T][32]
    const float* __restrict__ trans,    // [32][32] prev->cur
    float* __restrict__ out,            // [B]
    int T)
{
    const int  l  = threadIdx.x;
    const int  i  = l & 15;
    const int  hb = (l >> 4) & 1;       // batch within wave
    const int  th = l >> 5;             // tag half (my row's p-range)
    const int  c  = i + (th << 4);      // my tag
    const int  b  = blockIdx.x * 2 + hb;
    const bool hi = (l >= 32);

    const float L2E = 1.44269504088896340736f;

    // Packed E columns, pre-rotated to match the DPP allgather ordering:
    // w[k] = u[16*th + ((i-k)&15)]  ->  E2[k] = { E[p(k)][c], E[p(k)][c^16] }
    // trans[:,START] = -1e4 -> exp2f underflows to exactly 0 (sentinel semantics preserved)
    v2f E2[16];
#pragma unroll
    for (int k = 0; k < 16; ++k) {
        int p = (th << 4) + ((i - k) & 15);
        E2[k].x = exp2f(trans[p * 32 + c] * L2E);
        E2[k].y = exp2f(trans[p * 32 + (c ^ 16)] * L2E);
    }
    const float Eend = exp2f(trans[c * 32 + END_IX] * L2E);

    float u   = (c == START_IX) ? 1.0f : 0.0f;
    int   off = 0;    // renorm exponents only; the folded -6/step is added at the end

    const float* fp = frames + (size_t)b * T * K_TAGS + c;

    float fq[8];
#pragma unroll
    for (int j = 0; j < 8; ++j) fq[j] = fp[(size_t)j * K_TAGS];

    for (int t0 = 0; t0 < T; t0 += 8) {
#pragma unroll
        for (int j = 0; j < 8; ++j) {
            const int t = t0 + j;
            // g from frame prefetched 8 steps ago -> off the dependency chain
            float g = exp2f(fmaf(fq[j], L2E, -6.0f));

            int tn = t + 8; if (tn > T - 1) tn = T - 1;
            float fnew = fp[(size_t)tn * K_TAGS];

            // ---- pure-VALU allgather of u across my 16-lane row (15 DPP movs) ----
            float w0  = u;
            float w1  = ror16<1>(w0);
            float w2  = ror16<2>(w0);
            float w3  = ror16<2>(w1);
            float w4  = ror16<4>(w0);
            float w5  = ror16<4>(w1);
            float w6  = ror16<4>(w2);
            float w7  = ror16<4>(w3);
            float w8  = ror16<8>(w0);
            float w9  = ror16<8>(w1);
            float w10 = ror16<8>(w2);
            float w11 = ror16<8>(w3);
            float w12 = ror16<8>(w4);
            float w13 = ror16<8>(w5);
            float w14 = ror16<8>(w6);
            float w15 = ror16<8>(w7);

            // ---- two 16-long dots (own tag + partner tag), packed fp32 FMA ----
            v2f a0 = {0.0f, 0.0f}, a1 = {0.0f, 0.0f};
            a0 += (v2f){w0,  w0 } * E2[0];
            a1 += (v2f){w8,  w8 } * E2[8];
            a0 += (v2f){w1,  w1 } * E2[1];
            a1 += (v2f){w9,  w9 } * E2[9];
            a0 += (v2f){w2,  w2 } * E2[2];
            a1 += (v2f){w10, w10} * E2[10];
            a0 += (v2f){w3,  w3 } * E2[3];
            a1 += (v2f){w11, w11} * E2[11];
            a0 += (v2f){w4,  w4 } * E2[4];
            a1 += (v2f){w12, w12} * E2[12];
            a0 += (v2f){w5,  w5 } * E2[5];
            a1 += (v2f){w13, w13} * E2[13];
            a0 += (v2f){w6,  w6 } * E2[6];
            a1 += (v2f){w14, w14} * E2[14];
            a0 += (v2f){w7,  w7 } * E2[7];
            a1 += (v2f){w15, w15} * E2[15];

            float own = a0.x + a1.x;          // partial for my tag over my p-range
            float par = a0.y + a1.y;          // partial for partner tag over my p-range
            float v   = own + xswap32(par, hi);

            if (j == 7) {
                // batch-uniform renorm: max over all 32 u's (order-invariant -> bitwise
                // identical across the batch's lanes -> exact uniform power-of-2 scale)
                float m0 = fmaxf(fmaxf(w0,  w1),  fmaxf(w2,  w3));
                float m1 = fmaxf(fmaxf(w4,  w5),  fmaxf(w6,  w7));
                float m2 = fmaxf(fmaxf(w8,  w9),  fmaxf(w10, w11));
                float m3 = fmaxf(fmaxf(w12, w13), fmaxf(w14, w15));
                float mr = fmaxf(fmaxf(m0, m1), fmaxf(m2, m3));
                float M  = fmaxf(mr, xswap32(mr, hi));
                int   e  = (int)((__float_as_uint(M) >> 23) & 255u) - 127;
                g  *= __uint_as_float((uint32_t)(127 - e) << 23);
                off += e;
            }

            u = v * g;
            fq[j] = fnew;
        }
    }

    // final: score = ln2 * (off + 6T + log2( sum_c u[c] * exp(trans[c][END]) ))
    float wv = u * Eend;
    wv += __shfl_xor(wv, 1,  64);
    wv += __shfl_xor(wv, 2,  64);
    wv += __shfl_xor(wv, 4,  64);
    wv += __shfl_xor(wv, 8,  64);
    wv += __shfl_xor(wv, 32, 64);   // masks {1,2,4,8,32} span exactly my batch's 32 lanes

    if (i == 0 && th == 0) {
        double res = ((double)(off + 6 * T) + (double)log2f(wv)) * 0.693147180559945309417;
        out[b] = (float)res;
    }
}

extern "C" void kernel_launch(void* const* d_in, const int* in_sizes, int n_in,
                              void* d_out, int out_size, void* d_ws, size_t ws_size,
                              hipStream_t stream)
{
    const float* frames = (const float*)d_in[0];
    const float* trans  = (const float*)d_in[1];
    float* out = (float*)d_out;

    const int B = out_size;                     // 1024
    const int T = in_sizes[0] / (B * K_TAGS);   // 1024

    dim3 grid(B / 2), block(64);
    crf_fwd_kernel<<<grid, block, 0, stream>>>(frames, trans, out, T);
}

// Round 4
// 250.092 us; speedup vs baseline: 1.4018x; 1.4018x over previous
//
#include <hip/hip_runtime.h>
#include <stdint.h>

#define K_TAGS   32
#define START_IX 30
#define END_IX   31
#define WIN      32

typedef float v2f __attribute__((ext_vector_type(2)));

// DPP row_ror:N within each 16-lane row: dst[i] = src[(i-N)&15]
template<int N>
__device__ __forceinline__ float ror16(float x) {
    return __int_as_float(__builtin_amdgcn_mov_dpp(__float_as_int(x), 0x120 + N, 0xF, 0xF, false));
}

// value of x at lane l^32 (full-rate VALU permlane)
__device__ __forceinline__ float xswap32(float x, bool hi) {
    float a = x, b = x;
    asm volatile("v_permlane32_swap_b32 %0, %1" : "+v"(a), "+v"(b));
    return hi ? a : b;
}

// Lane map: i=l&15, batch-half hb=(l>>4)&1, tag-half th=l>>5, tag c=i+16*th.
// u[c] = exp(alpha[c]) * 2^-(off+6t), off tracked exactly via power-of-2 renorm.
// Frames staged 32 steps at a time into LDS (global_load_lds x8, double-buffered,
// single wave per block -> no barriers, just vmcnt). Step loop is pure VALU.
__global__ __launch_bounds__(64) void crf_fwd_kernel(
    const float* __restrict__ frames,   // [B][T][32]
    const float* __restrict__ trans,    // [32][32] prev->cur
    float* __restrict__ out,            // [B]
    int T)
{
    __shared__ float fbuf[2][WIN][64];  // [buf][dt][half*32+tag] = 16 KB

    const int  l  = threadIdx.x;
    const int  i  = l & 15;
    const int  hb = (l >> 4) & 1;
    const int  th = l >> 5;
    const int  c  = i + (th << 4);
    const int  b  = blockIdx.x * 2 + hb;
    const bool hi = (l >= 32);
    const float L2E = 1.44269504088896340736f;

    // E columns pre-rotated for the DPP allgather ordering; packed {own, partner} tag.
    // trans[:,START] = -1e4 -> exp2f underflows to exactly 0 (sentinel preserved).
    v2f E2[16];
#pragma unroll
    for (int k = 0; k < 16; ++k) {
        int p = (th << 4) + ((i - k) & 15);
        E2[k].x = exp2f(trans[p * 32 + c] * L2E);
        E2[k].y = exp2f(trans[p * 32 + (c ^ 16)] * L2E);
    }
    const float Eend = exp2f(trans[c * 32 + END_IX] * L2E);

    float u   = (c == START_IX) ? 1.0f : 0.0f;
    int   off = 0;

    // Staging-lane mapping: instr k writes LDS bytes [k*1024 + l*16, +16) of a buffer;
    // that slot is frames[b(sh)][t0 + 4k + (l>>4)][4*(l&7) .. +3].
    const int sh = (l >> 3) & 1;
    const float* sp = frames
        + ((size_t)(blockIdx.x * 2 + sh) * T + (l >> 4)) * K_TAGS + (l & 7) * 4;

    // prologue: stage window 0 into buffer 0
#pragma unroll
    for (int k = 0; k < 8; ++k)
        __builtin_amdgcn_global_load_lds(
            (const __attribute__((address_space(1))) unsigned int*)(sp + k * 128),
            (__attribute__((address_space(3))) unsigned int*)((char*)&fbuf[0][0][0] + k * 1024),
            16, 0, 0);

    int buf = 0;
    for (int t0 = 0; t0 < T; t0 += WIN) {
        // (1) current buffer's stage was issued a full window ago -> this wait is ~free,
        // and guarantees the global_load_lds -> ds_read ordering without a barrier.
        asm volatile("s_waitcnt vmcnt(0)" ::: "memory");
        __builtin_amdgcn_sched_barrier(0);

        // (2) bulk-read this window's 32 frame values (stride 256B: 2 lanes/bank, free)
        const float* fb = &fbuf[buf][0][(hb << 5) + c];
        float gq[WIN];
#pragma unroll
        for (int j = 0; j < WIN; ++j) gq[j] = fb[j * 64];
        __builtin_amdgcn_sched_barrier(0);

        // (3) stage NEXT window (clamped) into the other buffer — issued now, waited
        // at the top of the next window (~2600 cycles of compute in between).
        {
            int tn = t0 + WIN; if (tn > T - WIN) tn = T - WIN;   // wave-uniform clamp
            const float* spn = sp + (size_t)tn * K_TAGS;
            char* ldsn = (char*)&fbuf[buf ^ 1][0][0];
#pragma unroll
            for (int k = 0; k < 8; ++k)
                __builtin_amdgcn_global_load_lds(
                    (const __attribute__((address_space(1))) unsigned int*)(spn + k * 128),
                    (__attribute__((address_space(3))) unsigned int*)(ldsn + k * 1024),
                    16, 0, 0);
        }
        __builtin_amdgcn_sched_barrier(0);

        // (4) frames -> g, all off the u-chain
#pragma unroll
        for (int j = 0; j < WIN; ++j) gq[j] = exp2f(fmaf(gq[j], L2E, -6.0f));

        // (5) 32 recurrence steps: pure VALU/DPP, zero memory ops
#pragma unroll
        for (int j = 0; j < WIN; ++j) {
            float g = gq[j];

            float w0  = u;
            float w1  = ror16<1>(w0);
            float w2  = ror16<2>(w0);
            float w3  = ror16<2>(w1);
            float w4  = ror16<4>(w0);
            float w5  = ror16<4>(w1);
            float w6  = ror16<4>(w2);
            float w7  = ror16<4>(w3);
            float w8  = ror16<8>(w0);
            float w9  = ror16<8>(w1);
            float w10 = ror16<8>(w2);
            float w11 = ror16<8>(w3);
            float w12 = ror16<8>(w4);
            float w13 = ror16<8>(w5);
            float w14 = ror16<8>(w6);
            float w15 = ror16<8>(w7);

            v2f a0 = {0.0f, 0.0f}, a1 = {0.0f, 0.0f};
            a0 += (v2f){w0,  w0 } * E2[0];
            a1 += (v2f){w8,  w8 } * E2[8];
            a0 += (v2f){w1,  w1 } * E2[1];
            a1 += (v2f){w9,  w9 } * E2[9];
            a0 += (v2f){w2,  w2 } * E2[2];
            a1 += (v2f){w10, w10} * E2[10];
            a0 += (v2f){w3,  w3 } * E2[3];
            a1 += (v2f){w11, w11} * E2[11];
            a0 += (v2f){w4,  w4 } * E2[4];
            a1 += (v2f){w12, w12} * E2[12];
            a0 += (v2f){w5,  w5 } * E2[5];
            a1 += (v2f){w13, w13} * E2[13];
            a0 += (v2f){w6,  w6 } * E2[6];
            a1 += (v2f){w14, w14} * E2[14];
            a0 += (v2f){w7,  w7 } * E2[7];
            a1 += (v2f){w15, w15} * E2[15];

            float own = a0.x + a1.x;
            float par = a0.y + a1.y;
            float v   = own + xswap32(par, hi);

            if ((j & 7) == 7) {
                // batch-uniform exact power-of-2 renorm (order-invariant max)
                float m0 = fmaxf(fmaxf(w0,  w1),  fmaxf(w2,  w3));
                float m1 = fmaxf(fmaxf(w4,  w5),  fmaxf(w6,  w7));
                float m2 = fmaxf(fmaxf(w8,  w9),  fmaxf(w10, w11));
                float m3 = fmaxf(fmaxf(w12, w13), fmaxf(w14, w15));
                float mr = fmaxf(fmaxf(m0, m1), fmaxf(m2, m3));
                float M  = fmaxf(mr, xswap32(mr, hi));
                int   e  = (int)((__float_as_uint(M) >> 23) & 255u) - 127;
                g  *= __uint_as_float((uint32_t)(127 - e) << 23);
                off += e;
            }

            u = v * g;
        }
        buf ^= 1;
    }

    // final: score = ln2 * (off + 6T + log2( sum_c u[c] * exp(trans[c][END]) ))
    float wv = u * Eend;
    wv += __shfl_xor(wv, 1,  64);
    wv += __shfl_xor(wv, 2,  64);
    wv += __shfl_xor(wv, 4,  64);
    wv += __shfl_xor(wv, 8,  64);
    wv += __shfl_xor(wv, 32, 64);   // spans exactly my batch's 32 lanes

    if (i == 0 && th == 0) {
        double res = ((double)(off + 6 * T) + (double)log2f(wv)) * 0.693147180559945309417;
        out[b] = (float)res;
    }
}

extern "C" void kernel_launch(void* const* d_in, const int* in_sizes, int n_in,
                              void* d_out, int out_size, void* d_ws, size_t ws_size,
                              hipStream_t stream)
{
    const float* frames = (const float*)d_in[0];
    const float* trans  = (const float*)d_in[1];
    float* out = (float*)d_out;

    const int B = out_size;                     // 1024
    const int T = in_sizes[0] / (B * K_TAGS);   // 1024 (multiple of WIN)

    dim3 grid(B / 2), block(64);
    crf_fwd_kernel<<<grid, block, 0, stream>>>(frames, trans, out, T);
}